// Round 5
// baseline (43804.828 us; speedup 1.0000x reference)
//
#include <hip/hip_runtime.h>

// ---------------------------------------------------------------------------
// Persistent 2-layer LSTM for MI355X (gfx950). Round-9 structure (rewrite):
//   Batch-split pipeline, NO all-gather. 64 blocks x 512 thr:
//   block = (layer = bid&1 [XCD parity], chunk = bid>>1 of 16 batch rows).
//   - h/c recurrence is block-LOCAL (LDS A-fragments + register c-state).
//   - Weights pre-swizzled ONCE into bf16 MFMA B-fragments in ws (6.3 MB),
//     streamed from (XCD-local, read-only-cached) L2 every step.
//   - Only cross-block traffic: L0 -> L1 h0 mailbox (16KB/step/chunk) and
//     decode y-feedback (512B/step/chunk), via proven round-4 agent-scope
//     ast64/ald64 + stamp/poll protocol.
//   - MFMA 16x16x32 bf16; A-frag: row=lane&15, k=(lane>>4)*8+j;
//     C/D: col=lane&15, row=(lane>>4)*4+reg (verified mapping).
// ---------------------------------------------------------------------------

typedef __attribute__((ext_vector_type(8))) short bf16x8;
typedef __attribute__((ext_vector_type(4))) float f32x4;

#define MFMA16(a, b, c) __builtin_amdgcn_mfma_f32_16x16x32_bf16((a), (b), (c), 0, 0, 0)
#define DEV static __device__ __forceinline__

constexpr int kSeq = 128;   // encoder steps
constexpr int kT   = 175;   // total steps (47 decode after t=127)

// ws layout (bytes). Fragment = 64 lanes x 16B = 1KB.
constexpr size_t kWsW0  = 0;                        // L0: [32ut][17ks][4g] = 2176 KB
constexpr size_t kWsW1  = kWsW0 + 2176ull * 1024;   // L1: [32ut][32ks][4g] = 4096 KB
constexpr size_t kWsWFC = kWsW1 + 4096ull * 1024;   // FC: [16ks] = 16 KB
constexpr size_t kWsMbH = kWsWFC + 16ull * 1024;    // h0 mbox [2][32] x 16KB = 1 MB
constexpr size_t kWsMbY = kWsMbH + 2ull * 32 * 16384;  // y mbox [2][32] x 512B
constexpr size_t kWsFlg = kWsMbY + 2ull * 32 * 512;    // 256 slots x 64B
constexpr size_t kWsEnd = kWsFlg + 256ull * 64;
constexpr size_t kWsZeroBegin = kWsFlg;
constexpr size_t kWsZeroSize  = kWsEnd - kWsFlg;
// flag slots: f_h0[c]=c, f_h0c[c]=32+c, f_y[c]=64+c, f_yc[c]=96+c, f_w[b]=128+b

DEV unsigned short f2bf(float f) {
  unsigned u = __float_as_uint(f);
  u += 0x7fffu + ((u >> 16) & 1u);
  return (unsigned short)(u >> 16);
}
DEV float sigf(float v) { return 1.0f / (1.0f + __expf(-v)); }
DEV float tanhf_(float v) { float e = __expf(2.0f * v); return 1.0f - 2.0f / (e + 1.0f); }

// agent-scope (device-coherent) primitives — round-4 proven -----------------
DEV unsigned ald(const unsigned* p) {
  return __hip_atomic_load(p, __ATOMIC_RELAXED, __HIP_MEMORY_SCOPE_AGENT);
}
DEV void ast(unsigned* p, unsigned v) {
  __hip_atomic_store(p, v, __ATOMIC_RELAXED, __HIP_MEMORY_SCOPE_AGENT);
}
DEV unsigned long long ald64(const unsigned long long* p) {
  return __hip_atomic_load(p, __ATOMIC_RELAXED, __HIP_MEMORY_SCOPE_AGENT);
}
DEV void ast64(unsigned long long* p, unsigned long long v) {
  __hip_atomic_store(p, v, __ATOMIC_RELAXED, __HIP_MEMORY_SCOPE_AGENT);
}
DEV float aldf(const float* p) {
  return __hip_atomic_load(p, __ATOMIC_RELAXED, __HIP_MEMORY_SCOPE_AGENT);
}
DEV void astf(float* p, float v) {
  __hip_atomic_store(p, v, __ATOMIC_RELAXED, __HIP_MEMORY_SCOPE_AGENT);
}
DEV void relwait() {
  __atomic_signal_fence(__ATOMIC_SEQ_CST);
  __builtin_amdgcn_s_waitcnt(0);
  __atomic_signal_fence(__ATOMIC_SEQ_CST);
}
DEV bool pollw(const unsigned* slot, unsigned thr) {
  for (int it = 0; it < (1 << 22); ++it) {
    const unsigned v = ald(slot);
    if (__ballot(v < thr) == 0ull) {
      __atomic_signal_fence(__ATOMIC_ACQUIRE);
      return true;
    }
    __builtin_amdgcn_s_sleep(2);
  }
  return false;
}

__global__ __launch_bounds__(512, 2) void lstm_persist(
    const float* __restrict__ x, const float* __restrict__ ft,
    const float* __restrict__ h0in, const float* __restrict__ c0in,
    const float* __restrict__ wih0, const float* __restrict__ whh0,
    const float* __restrict__ bih0, const float* __restrict__ bhh0,
    const float* __restrict__ wih1, const float* __restrict__ whh1,
    const float* __restrict__ bih1, const float* __restrict__ bhh1,
    const float* __restrict__ fcw, const float* __restrict__ fcb,
    float* __restrict__ out, char* __restrict__ ws) {
  // xh: [parity 2][slice 32][lane 64][elem 8] bf16 A-fragments.
  //   L0: slices 0..15 = h0 (k=32..543). L1: 0..15 = h0(t), 16..31 = h1(t-1).
  __shared__ __attribute__((aligned(16))) unsigned short xh[2 * 32 * 512];
  __shared__ float biasl[2048];       // [gate 4][unit 512]
  __shared__ float xbuf[2 * 512];     // L0 encode x double-buffer [16 r][32]
  __shared__ float ftbuf[16 * 24];    // L0 decode time-features

  const int bid = blockIdx.x;
  const int layer = bid & 1;          // parity -> layer-per-XCD separation
  const int c = bid >> 1;             // batch chunk (16 rows)
  const int tid = threadIdx.x;
  const int wv = tid >> 6;
  const int lane = tid & 63;
  const int col = lane & 15;
  const int kg = lane >> 4;

  unsigned* flg = (unsigned*)(ws + kWsFlg);
  auto fslot = [&](int s) { return flg + s * 16; };
  unsigned short* w0 = (unsigned short*)(ws + kWsW0);
  unsigned short* w1 = (unsigned short*)(ws + kWsW1);
  unsigned short* wfc = (unsigned short*)(ws + kWsWFC);

  bool alive = true;

  // ---------------- one-time: cooperative weight fragment fill --------------
  {
    const int gid = bid * 512 + tid;
    for (int idx = gid; idx < 6288 * 64; idx += 64 * 512) {
      const int frag = idx >> 6, li = idx & 63;
      const int fc_ = li & 15, fk = li >> 4;
      const float* src = nullptr;
      unsigned short* dst;
      if (frag < 2176) {                       // L0: frag = (ut*17+ks)*4+g
        const int g = frag & 3, q = frag >> 2;
        const int ks = q % 17, ut = q / 17;
        const int n = g * 512 + ut * 16 + fc_;
        const int k0 = ks * 32 + fk * 8;
        src = (k0 < 32) ? (wih0 + n * 32 + k0) : (whh0 + (size_t)n * 512 + (k0 - 32));
        dst = w0 + (size_t)frag * 512 + li * 8;
      } else if (frag < 6272) {                // L1: frag = (ut*32+ks)*4+g
        const int f2 = frag - 2176;
        const int g = f2 & 3, q = f2 >> 2;
        const int ks = q & 31, ut = q >> 5;
        const int n = g * 512 + ut * 16 + fc_;
        const int k0 = ks * 32 + fk * 8;
        src = (k0 < 512) ? (wih1 + (size_t)n * 512 + k0)
                         : (whh1 + (size_t)n * 512 + (k0 - 512));
        dst = w1 + (size_t)f2 * 512 + li * 8;
      } else {                                 // FC: 16 frags, cols 8..15 zero
        const int ks = frag - 6272;
        const int k0 = ks * 32 + fk * 8;
        src = (fc_ < 8) ? (fcw + (size_t)fc_ * 512 + k0) : nullptr;
        dst = wfc + (size_t)ks * 512 + li * 8;
      }
      union { unsigned short s[8]; unsigned long long u[2]; } v;
      if (src) {
#pragma unroll
        for (int j = 0; j < 8; ++j) v.s[j] = f2bf(src[j]);
      } else { v.u[0] = 0ull; v.u[1] = 0ull; }
      ast64((unsigned long long*)dst, v.u[0]);
      ast64((unsigned long long*)dst + 1, v.u[1]);
    }
    relwait();
    __syncthreads();
    if (tid == 0) ast(fslot(128 + bid), 1u);
  }

  // ---------------- local init (overlaps weight handshake) ------------------
  for (int i2 = tid; i2 < 2048; i2 += 512)
    biasl[i2] = layer ? (bih1[i2] + bhh1[i2]) : (bih0[i2] + bhh0[i2]);
  const int HB = layer ? 16 : 0;
  for (int i2 = tid; i2 < 8192; i2 += 512) {   // h(-1) broadcast into parity 0
    const int sl = i2 >> 9, rem = i2 & 511;
    const int l2 = rem >> 3, j = rem & 7;
    const int u = sl * 32 + (l2 >> 4) * 8 + j;
    xh[(HB + sl) * 512 + rem] = f2bf(h0in[layer * 512 + u]);
  }
  float cst[4][4];
#pragma unroll
  for (int q = 0; q < 4; ++q) {
    const float cv = c0in[layer * 512 + (wv * 4 + q) * 16 + col];
    cst[q][0] = cst[q][1] = cst[q][2] = cst[q][3] = cv;
  }
  float fcbr = 0.0f;
  if (layer && col < 8) fcbr = fcb[col];
  if (layer == 0 && tid < 128) {               // prefetch x(0)
    const int r = tid >> 3, cc = (tid & 7) * 4;
    *(float4*)&xbuf[r * 32 + cc] =
        *(const float4*)&x[((size_t)c * 16 + r) * 32 + cc];
  }
  // weight handshake: all 64 fill-flags, then acquire (cache-invalidate)
  if (wv == 0) alive = pollw(fslot(128 + lane), 1u);
  __syncthreads();
  (void)__hip_atomic_load(fslot(128 + (tid & 63)), __ATOMIC_ACQUIRE,
                          __HIP_MEMORY_SCOPE_AGENT);
  __syncthreads();

  if (layer == 0) {
    // ================================ L0 ================================
    for (int t = 0; t < kT; ++t) {
      const int p = t & 1;
      if (wv == 0 && alive) {  // lane0: mailbox WAR; lane1: y(t-1) ready
        const unsigned* sl_ = fslot(32 + c);
        unsigned th_ = (unsigned)t;
        if (lane == 1 && t >= kSeq) { sl_ = fslot(64 + c); th_ = (unsigned)(t + 1); }
        alive = pollw(sl_, th_);
      }
      __syncthreads();
      // x-part A-fragment (k = 0..31) in registers
      bf16x8 xfrag;
      if (t < kSeq) {
        const float* xb = &xbuf[p * 512 + col * 32 + kg * 8];
#pragma unroll
        for (int j = 0; j < 8; ++j) xfrag[j] = (short)f2bf(xb[j]);
      } else {
        if (kg == 0) {  // k 0..7 = y(t-1)
          const float* yp = (const float*)(ws + kWsMbY) +
                            ((size_t)((t - 1) & 1) * 32 + c) * 128 + col * 8;
#pragma unroll
          for (int j = 0; j < 8; ++j) xfrag[j] = (short)f2bf(aldf(yp + j));
        } else {        // k 8..31 = ft[t-128]
          const float* fp = &ftbuf[col * 24 + kg * 8 - 8];
#pragma unroll
          for (int j = 0; j < 8; ++j) xfrag[j] = (short)f2bf(fp[j]);
        }
      }
      __syncthreads();  // all mb_y / ftbuf reads done
      if (t >= kSeq && tid == 0) ast(fslot(96 + c), (unsigned)(t + 1));
      // prefetch next step's x-part inputs (no dependencies)
      if (t + 1 < kSeq) {
        if (tid < 128) {
          const int r = tid >> 3, cc = (tid & 7) * 4;
          *(float4*)&xbuf[((t + 1) & 1) * 512 + r * 32 + cc] =
              *(const float4*)&x[((size_t)(t + 1) * 512 + c * 16 + r) * 32 + cc];
        }
      } else if (t + 1 < kT) {
        if (tid < 96) {
          const int r = tid / 6, m = (tid - r * 6) * 4;
          *(float4*)&ftbuf[r * 24 + m] =
              *(const float4*)&ft[((size_t)(t + 1 - kSeq) * 512 + c * 16 + r) * 24 + m];
        }
      }
      // GEMM + cell, 4 unit-tiles per wave
#pragma unroll
      for (int q = 0; q < 4; ++q) {
        const int ut = wv * 4 + q;
        const unsigned short* wp = w0 + (size_t)ut * 17 * 4 * 512;
        const float b0 = biasl[ut * 16 + col];
        const float b1 = biasl[512 + ut * 16 + col];
        const float b2 = biasl[1024 + ut * 16 + col];
        const float b3 = biasl[1536 + ut * 16 + col];
        f32x4 a0 = {b0, b0, b0, b0}, a1 = {b1, b1, b1, b1};
        f32x4 a2 = {b2, b2, b2, b2}, a3 = {b3, b3, b3, b3};
        a0 = MFMA16(xfrag, *(const bf16x8*)(wp + 0 * 512 + lane * 8), a0);
        a1 = MFMA16(xfrag, *(const bf16x8*)(wp + 1 * 512 + lane * 8), a1);
        a2 = MFMA16(xfrag, *(const bf16x8*)(wp + 2 * 512 + lane * 8), a2);
        a3 = MFMA16(xfrag, *(const bf16x8*)(wp + 3 * 512 + lane * 8), a3);
        bf16x8 Ab[2][2], Bb[2][8];
        auto issue = [&](int bf, int s0) {
#pragma unroll
          for (int e = 0; e < 2; ++e) {
            Ab[bf][e] = *(const bf16x8*)&xh[(p * 32 + (s0 + e)) * 512 + lane * 8];
#pragma unroll
            for (int g = 0; g < 4; ++g)
              Bb[bf][e * 4 + g] =
                  *(const bf16x8*)(wp + ((size_t)(1 + s0 + e) * 4 + g) * 512 + lane * 8);
          }
        };
        issue(0, 0);
#pragma unroll
        for (int s0 = 0; s0 < 16; s0 += 2) {
          const int cb = (s0 >> 1) & 1;
          if (s0 + 2 < 16) issue(cb ^ 1, s0 + 2);
#pragma unroll
          for (int e = 0; e < 2; ++e) {
            const bf16x8 a = Ab[cb][e];
            a0 = MFMA16(a, Bb[cb][e * 4 + 0], a0);
            a1 = MFMA16(a, Bb[cb][e * 4 + 1], a1);
            a2 = MFMA16(a, Bb[cb][e * 4 + 2], a2);
            a3 = MFMA16(a, Bb[cb][e * 4 + 3], a3);
          }
        }
#pragma unroll
        for (int r = 0; r < 4; ++r) {   // lane-local cell update
          float cv = cst[q][r];
          cv = sigf(a1[r]) * cv + sigf(a0[r]) * tanhf_(a2[r]);
          cst[q][r] = cv;
          const float hv = sigf(a3[r]) * tanhf_(cv);
          const int u = ut * 16 + col;
          const int sl2 = u >> 5;
          const int l2 = (kg * 4 + r) | (((u >> 3) & 3) << 4);
          xh[((p ^ 1) * 32 + sl2) * 512 + l2 * 8 + (lane & 7)] = f2bf(hv);
        }
      }
      __syncthreads();
      {  // publish h0(t) mailbox (frag-layout verbatim copy, 16KB)
        const unsigned long long* srcl =
            (const unsigned long long*)&xh[((p ^ 1) * 32) * 512];
        unsigned long long* mb =
            (unsigned long long*)(ws + kWsMbH + ((size_t)p * 32 + c) * 16384);
#pragma unroll
        for (int i2 = 0; i2 < 4; ++i2) {
          const int idx = tid + i2 * 512;
          ast64(mb + idx, srcl[idx]);
        }
      }
      relwait();
      __syncthreads();
      if (tid == 0) ast(fslot(c), (unsigned)(t + 2));
    }
  } else {
    // ================================ L1 ================================
    for (int t = 0; t < kT; ++t) {
      const int p = t & 1;
      if (wv == 0 && alive) {  // lane0: h0(t) ready; lane1: y-mbox WAR
        const unsigned* sl_ = fslot(c);
        unsigned th_ = (unsigned)(t + 2);
        if (lane == 1 && t >= kSeq + 1) { sl_ = fslot(96 + c); th_ = (unsigned)t; }
        alive = pollw(sl_, th_);
      }
      __syncthreads();
      {  // copy-in h0(t): mailbox -> slices 0..15 of parity p
        const unsigned long long* mb =
            (const unsigned long long*)(ws + kWsMbH + ((size_t)p * 32 + c) * 16384);
        unsigned long long* dstl = (unsigned long long*)&xh[(p * 32) * 512];
#pragma unroll
        for (int i2 = 0; i2 < 4; ++i2) {
          const int idx = tid + i2 * 512;
          dstl[idx] = ald64(mb + idx);
        }
      }
      __syncthreads();
      if (tid == 0) ast(fslot(32 + c), (unsigned)(t + 2));
#pragma unroll
      for (int q = 0; q < 4; ++q) {
        const int ut = wv * 4 + q;
        const unsigned short* wp = w1 + (size_t)ut * 32 * 4 * 512;
        const float b0 = biasl[ut * 16 + col];
        const float b1 = biasl[512 + ut * 16 + col];
        const float b2 = biasl[1024 + ut * 16 + col];
        const float b3 = biasl[1536 + ut * 16 + col];
        f32x4 a0 = {b0, b0, b0, b0}, a1 = {b1, b1, b1, b1};
        f32x4 a2 = {b2, b2, b2, b2}, a3 = {b3, b3, b3, b3};
        bf16x8 Ab[2][2], Bb[2][8];
        auto issue = [&](int bf, int s0) {
#pragma unroll
          for (int e = 0; e < 2; ++e) {
            Ab[bf][e] = *(const bf16x8*)&xh[(p * 32 + (s0 + e)) * 512 + lane * 8];
#pragma unroll
            for (int g = 0; g < 4; ++g)
              Bb[bf][e * 4 + g] =
                  *(const bf16x8*)(wp + ((size_t)(s0 + e) * 4 + g) * 512 + lane * 8);
          }
        };
        issue(0, 0);
#pragma unroll
        for (int s0 = 0; s0 < 32; s0 += 2) {
          const int cb = (s0 >> 1) & 1;
          if (s0 + 2 < 32) issue(cb ^ 1, s0 + 2);
#pragma unroll
          for (int e = 0; e < 2; ++e) {
            const bf16x8 a = Ab[cb][e];
            a0 = MFMA16(a, Bb[cb][e * 4 + 0], a0);
            a1 = MFMA16(a, Bb[cb][e * 4 + 1], a1);
            a2 = MFMA16(a, Bb[cb][e * 4 + 2], a2);
            a3 = MFMA16(a, Bb[cb][e * 4 + 3], a3);
          }
        }
#pragma unroll
        for (int r = 0; r < 4; ++r) {
          float cv = cst[q][r];
          cv = sigf(a1[r]) * cv + sigf(a0[r]) * tanhf_(a2[r]);
          cst[q][r] = cv;
          const float hv = sigf(a3[r]) * tanhf_(cv);
          const int u = ut * 16 + col;
          const int sl2 = 16 + (u >> 5);
          const int l2 = (kg * 4 + r) | (((u >> 3) & 3) << 4);
          xh[((p ^ 1) * 32 + sl2) * 512 + l2 * 8 + (lane & 7)] = f2bf(hv);
        }
      }
      __syncthreads();
      if (t >= kSeq - 1) {  // y(t) = fcw*h1(t)+fcb: wave0, 16 MFMAs
        if (wv == 0) {
          f32x4 ya = {fcbr, fcbr, fcbr, fcbr};
#pragma unroll
          for (int kf = 0; kf < 16; ++kf) {
            const bf16x8 a =
                *(const bf16x8*)&xh[((p ^ 1) * 32 + 16 + kf) * 512 + lane * 8];
            const bf16x8 b = *(const bf16x8*)(wfc + (size_t)kf * 512 + lane * 8);
            ya = MFMA16(a, b, ya);
          }
          if (col < 8) {
            float* yp = (float*)(ws + kWsMbY) + ((size_t)p * 32 + c) * 128;
#pragma unroll
            for (int r = 0; r < 4; ++r) {
              const int row = kg * 4 + r;
              astf(yp + row * 8 + col, ya[r]);
              out[((size_t)(t - (kSeq - 1)) * 512 + c * 16 + row) * 8 + col] = ya[r];
            }
          }
        }
        relwait();
        __syncthreads();
        if (tid == 0) ast(fslot(64 + c), (unsigned)(t + 2));
      }
    }
  }
}

extern "C" void kernel_launch(void* const* d_in, const int* in_sizes, int n_in,
                              void* d_out, int out_size, void* d_ws, size_t ws_size,
                              hipStream_t stream) {
  (void)in_sizes; (void)n_in; (void)out_size; (void)ws_size;
  hipMemsetAsync((char*)d_ws + kWsZeroBegin, 0, kWsZeroSize, stream);

  const float* x    = (const float*)d_in[0];
  const float* ft   = (const float*)d_in[1];
  const float* h0in = (const float*)d_in[2];
  const float* c0in = (const float*)d_in[3];
  const float* wih0 = (const float*)d_in[4];
  const float* whh0 = (const float*)d_in[5];
  const float* bih0 = (const float*)d_in[6];
  const float* bhh0 = (const float*)d_in[7];
  const float* wih1 = (const float*)d_in[8];
  const float* whh1 = (const float*)d_in[9];
  const float* bih1 = (const float*)d_in[10];
  const float* bhh1 = (const float*)d_in[11];
  const float* fcw  = (const float*)d_in[12];
  const float* fcb  = (const float*)d_in[13];
  float* out = (float*)d_out;
  char* ws = (char*)d_ws;

  void* args[] = {&x, &ft, &h0in, &c0in, &wih0, &whh0, &bih0, &bhh0,
                  &wih1, &whh1, &bih1, &bhh1, &fcw, &fcb, &out, &ws};
  hipError_t err = hipLaunchCooperativeKernel((void*)lstm_persist, dim3(64),
                                              dim3(512), args, 0, stream);
  if (err != hipSuccess) {
    lstm_persist<<<dim3(64), dim3(512), 0, stream>>>(
        x, ft, h0in, c0in, wih0, whh0, bih0, bhh0,
        wih1, whh1, bih1, bhh1, fcw, fcb, out, ws);
  }
}

// Round 6
// 5892.016 us; speedup vs baseline: 7.4346x; 7.4346x over previous
//
#include <hip/hip_runtime.h>

// ---------------------------------------------------------------------------
// Persistent 2-layer LSTM for MI355X (gfx950). Round-10 structure:
//   - EXACT round-4/8 verified base (3390 us): 512 blk x 256 thr, reg
//     weights, fragment-major h regions, 2-deep ping-pong, agent-scope
//     stores + stamp/poll, yacc decode machinery, rdflag early WAR release.
//   - NEW (the one lever): K-loop h reads are PLAIN CACHEABLE loads, with an
//     agent ACQUIRE fence (buffer_inv) once per step after the poll.
//     Rationale: round-4 is IF-BW-bound (48 MB/step of agent loads that
//     bypass L1/L2 = 2.5 TB/s sustained). All 32 hc-blocks of a (layer,bc)
//     group read the SAME 64KB region and sit on the SAME XCD (bid%8=bc),
//     so L2-cached reads cut IF traffic up to 32x. Producer side unchanged
//     (proven write-through + relwait + stamp); freshness via inv-before-
//     read; WAR safety via existing flags (regions monotonic).
// ---------------------------------------------------------------------------

typedef __attribute__((ext_vector_type(8))) short bf16x8;
typedef __attribute__((ext_vector_type(16))) float f32x16;

#define MFMA32(a, b, c) __builtin_amdgcn_mfma_f32_32x32x16_bf16((a), (b), (c), 0, 0, 0)
#define DEV static __device__ __forceinline__

constexpr int kSeq = 128;          // encoder steps
constexpr int kT = 175;            // total lstm steps
constexpr int kRB = 65536;         // bytes per (parity,layer,bc) h region

// workspace layout (bytes)
constexpr size_t kWsHbuf = 0;                               // [2][2][8] regions = 2 MB
constexpr size_t kWsYacc = 2ull * 2 * 8 * kRB;              // [2][512][8] f32 = 32 KB
constexpr size_t kWsFlag = kWsYacc + 2ull * 512 * 8 * 4;    // [2][8][32] x 64B = 32 KB
constexpr size_t kWsRc   = kWsFlag + 2ull * 8 * 32 * 64;    // [2][8] x 64B
constexpr size_t kWsRd   = kWsRc + 2ull * 8 * 64;           // [8][32] x 64B rdflags
constexpr size_t kWsEnd  = kWsRd + 8ull * 32 * 64;
constexpr size_t kWsZeroBegin = kWsYacc;
constexpr size_t kWsZeroSize  = kWsEnd - kWsYacc;

DEV unsigned short f2bf(float f) {
  unsigned u = __float_as_uint(f);
  u += 0x7fffu + ((u >> 16) & 1u);
  return (unsigned short)(u >> 16);
}
DEV float bf2f(unsigned short s) { return __uint_as_float(((unsigned)s) << 16); }
DEV float sigf(float v) { return 1.0f / (1.0f + __expf(-v)); }
DEV float tanhf_(float v) { float e = __expf(2.0f * v); return 1.0f - 2.0f / (e + 1.0f); }
DEV f32x16 zero16() {
  f32x16 z;
#pragma unroll
  for (int i = 0; i < 16; ++i) z[i] = 0.0f;
  return z;
}
DEV bf16x8 pack8(const float* p) {
  float4 a = *(const float4*)p;
  float4 b = *(const float4*)(p + 4);
  bf16x8 r;
  r[0] = (short)f2bf(a.x); r[1] = (short)f2bf(a.y);
  r[2] = (short)f2bf(a.z); r[3] = (short)f2bf(a.w);
  r[4] = (short)f2bf(b.x); r[5] = (short)f2bf(b.y);
  r[6] = (short)f2bf(b.z); r[7] = (short)f2bf(b.w);
  return r;
}

// device-coherent (agent-scope) primitives ---------------------------------
DEV unsigned ald(const unsigned* p) {
  return __hip_atomic_load(p, __ATOMIC_RELAXED, __HIP_MEMORY_SCOPE_AGENT);
}
DEV void ast(unsigned* p, unsigned v) {
  __hip_atomic_store(p, v, __ATOMIC_RELAXED, __HIP_MEMORY_SCOPE_AGENT);
}
DEV unsigned long long ald64(const unsigned long long* p) {
  return __hip_atomic_load(p, __ATOMIC_RELAXED, __HIP_MEMORY_SCOPE_AGENT);
}
DEV void ast64(unsigned long long* p, unsigned long long v) {
  __hip_atomic_store(p, v, __ATOMIC_RELAXED, __HIP_MEMORY_SCOPE_AGENT);
}
DEV float aldf(const float* p) {
  return __hip_atomic_load(p, __ATOMIC_RELAXED, __HIP_MEMORY_SCOPE_AGENT);
}
DEV void astf(float* p, float v) {
  __hip_atomic_store(p, v, __ATOMIC_RELAXED, __HIP_MEMORY_SCOPE_AGENT);
}
DEV void relwait() {  // drain own coherent stores to the coherence point
  __atomic_signal_fence(__ATOMIC_SEQ_CST);
  __builtin_amdgcn_s_waitcnt(0);
  __atomic_signal_fence(__ATOMIC_SEQ_CST);
}
DEV void acqinv() {  // agent acquire: invalidate L1 + stale L2 before reads
  __builtin_amdgcn_fence(__ATOMIC_ACQUIRE, "agent");
}
// wave-parallel bounded poll: every lane has its own slot/threshold.
DEV bool pollw(const unsigned* slot, unsigned thr) {
  for (int it = 0; it < (1 << 22); ++it) {
    const unsigned v = ald(slot);
    if (__ballot(v < thr) == 0ull) {
      __atomic_signal_fence(__ATOMIC_ACQUIRE);
      return true;
    }
    __builtin_amdgcn_s_sleep(8);
  }
  return false;
}

// parts: [16 (kw,gate)][64 r][17 pad] bf16
#define PARTS_WRITE(accv, ms_, ns_)                                           \
  { const int gate_ = (ns_)*2 + gbit;                                         \
    _Pragma("unroll") for (int rg = 0; rg < 16; ++rg) {                       \
      const int r_ = (ms_)*32 + (rg & 3) + 4 * hi5 + 8 * (rg >> 2);           \
      partsB[((kw * 4 + gate_) * 64 + r_) * 17 + l15] = f2bf((accv)[rg]);     \
    } }

__global__ __launch_bounds__(256, 2) void lstm_persist(
    const float* __restrict__ x, const float* __restrict__ ft,
    const float* __restrict__ h0in, const float* __restrict__ c0in,
    const float* __restrict__ wih0, const float* __restrict__ whh0,
    const float* __restrict__ bih0, const float* __restrict__ bhh0,
    const float* __restrict__ wih1, const float* __restrict__ whh1,
    const float* __restrict__ bih1, const float* __restrict__ bhh1,
    const float* __restrict__ fcw, const float* __restrict__ fcb,
    float* __restrict__ out, char* __restrict__ ws) {
  __shared__ __attribute__((aligned(16))) unsigned short partsB[16 * 64 * 17];
  __shared__ __attribute__((aligned(16))) unsigned short xin[64 * 40];
  __shared__ __attribute__((aligned(16))) unsigned short hloc[64 * 24];
  __shared__ float biasl[4][16];
  __shared__ float fcwl[8][16];
  __shared__ unsigned bflag;

  const int bid = blockIdx.x;
  const int layer = bid >> 8;
  const int idx = bid & 255;
  const int bc = idx & 7;
  const int hc = idx >> 3;
  const int b0 = bc * 64;
  const int u0 = hc * 16;
  const int tid = threadIdx.x;
  const int kw = tid >> 6;
  const int lane = tid & 63;
  const int l31 = lane & 31, l15 = lane & 15, hi5 = lane >> 5, gbit = (lane >> 4) & 1;

  char* hbuf = ws + kWsHbuf;
  float* yacc = (float*)(ws + kWsYacc);
  unsigned* flg = (unsigned*)(ws + kWsFlag);
  unsigned* rc = (unsigned*)(ws + kWsRc);
  unsigned* rdf = (unsigned*)(ws + kWsRd);

  auto fslot = [&](int l, int b, int h) { return flg + (((l * 8) + b) * 32 + h) * 16; };
  auto rdslot = [&](int b, int h) { return rdf + (b * 32 + h) * 16; };
  auto region = [&](int p, int l, int b) -> char* {
    return hbuf + (size_t)(((p * 2) + l) * 8 + b) * kRB;
  };

  bool alive = true;  // wave0 lanes: poll timeout kill-switch

  // ---- one-time: weights -> registers (bf16 B-fragments), index by m ----
  // wave kw handles ksteps jin = kw + 4m.  B-frag: n=lane&31, k=hi5*8+j.
  bf16x8 wf[2][16];
#pragma unroll
  for (int ns = 0; ns < 2; ++ns) {
    const int gate = ns * 2 + gbit;
    const int wrow = gate * 512 + u0 + l15;
    if (layer) {
#pragma unroll
      for (int m = 0; m < 16; ++m) {
        const int jg = kw + 4 * m;
        const int k0 = jg * 16 + hi5 * 8;
        const float* p = (k0 < 512) ? (wih1 + wrow * 512 + k0)
                                    : (whh1 + wrow * 512 + (k0 - 512));
        wf[ns][m] = pack8(p);
      }
    } else {
#pragma unroll
      for (int m = 0; m < 8; ++m) {
        const int jg = kw + 4 * m;
        wf[ns][m] = pack8(whh0 + wrow * 512 + jg * 16 + hi5 * 8);
      }
      if (kw < 2) wf[ns][8] = pack8(wih0 + wrow * 32 + kw * 16 + hi5 * 8);
    }
  }

  if (tid < 64) {
    const int g = tid >> 4, h = tid & 15;
    const int row = g * 512 + u0 + h;
    biasl[g][h] = layer ? (bih1[row] + bhh1[row]) : (bih0[row] + bhh0[row]);
  }
  if (layer && tid >= 64 && tid < 192) {
    const int t2 = tid - 64;
    fcwl[t2 >> 4][t2 & 15] = fcw[(t2 >> 4) * 512 + u0 + (t2 & 15)];
  }

  const int own_h = tid & 15;
  const int own_r0 = (tid >> 4) * 4;
  float cst[4];
  {
    const float cv = c0in[layer * 512 + u0 + own_h];
    cst[0] = cst[1] = cst[2] = cst[3] = cv;
  }

  // ---- prologue: write h(-1) into fragment-major region, stamp 1 ----
  {
    char* dst = region(layer ? 0 : 1, layer, bc);
    if (tid < 128) {
      const int r = tid >> 1, half = tid & 1;
      union { unsigned short s[8]; unsigned long long u[2]; } v;
#pragma unroll
      for (int k2 = 0; k2 < 8; ++k2)
        v.s[k2] = f2bf(h0in[layer * 512 + u0 + half * 8 + k2]);
      unsigned long long* dp =
          (unsigned long long*)(dst + ((u0 >> 3) + half) * 1024 + r * 16);
      ast64(dp, v.u[0]); ast64(dp + 1, v.u[1]);
    }
    relwait();
    __syncthreads();
    if (tid == 0) ast(fslot(layer, bc, hc), 1u);
  }

  auto xin_store = [&](int r, int c4, float4 v) {
    const int gx = c4 >> 3, half = (c4 >> 2) & 1;
    uint2 pv;
    pv.x = (unsigned)f2bf(v.x) | ((unsigned)f2bf(v.y) << 16);
    pv.y = (unsigned)f2bf(v.z) | ((unsigned)f2bf(v.w) << 16);
    *(uint2*)&xin[r * 40 + ((gx ^ (r & 3)) << 3) + half * 4] = pv;
  };

  auto cell_update = [&]() {
#pragma unroll
    for (int i = 0; i < 4; ++i) {
      const int r = own_r0 + i;
      float ig = biasl[0][own_h], fg = biasl[1][own_h];
      float gg = biasl[2][own_h], og = biasl[3][own_h];
#pragma unroll
      for (int w2 = 0; w2 < 4; ++w2) {
        ig += bf2f(partsB[((w2 * 4 + 0) * 64 + r) * 17 + own_h]);
        fg += bf2f(partsB[((w2 * 4 + 1) * 64 + r) * 17 + own_h]);
        gg += bf2f(partsB[((w2 * 4 + 2) * 64 + r) * 17 + own_h]);
        og += bf2f(partsB[((w2 * 4 + 3) * 64 + r) * 17 + own_h]);
      }
      const float cv = sigf(fg) * cst[i] + sigf(ig) * tanhf_(gg);
      cst[i] = cv;
      hloc[r * 24 + own_h] = f2bf(sigf(og) * tanhf_(cv));
    }
  };

  auto h_publish = [&](char* dst) {  // 64 r x 16 units, coherent u64 stores
    if (tid < 128) {
      const int r = tid >> 1, half = tid & 1;
      union { uint4 q; unsigned long long u[2]; } v;
      v.q = *(const uint4*)&hloc[r * 24 + half * 8];
      unsigned long long* dp =
          (unsigned long long*)(dst + ((u0 >> 3) + half) * 1024 + r * 16);
      ast64(dp, v.u[0]); ast64(dp + 1, v.u[1]);
    }
  };

  if (layer == 0) {
    // =========================== LAYER 0 ===========================
    for (int t = 0; t < kT; ++t) {
      // waits: h0(t-1) ready (stamp>=t+1);
      // encode WAR: rdflag >= t (L1 consumed h0(t-2));
      // decode: flag1 >= t+1 (y(t-1) value ready).
      if (kw == 0 && alive) {
        const unsigned* slot = (lane < 32)
            ? fslot(0, bc, lane)
            : ((t < kSeq) ? rdslot(bc, lane - 32) : fslot(1, bc, lane - 32));
        const unsigned thr = (lane < 32)
            ? (unsigned)(t + 1)
            : (unsigned)((t < kSeq) ? t : t + 1);
        alive = pollw(slot, thr);
      }
      __syncthreads();
      acqinv();  // invalidate stale L1/L2 lines; h reads below are cacheable

      if (t < kSeq) {
#pragma unroll
        for (int it = 0; it < 2; ++it) {
          const int u = tid + it * 256;
          const int r = u >> 3, c4 = (u & 7) * 4;
          xin_store(r, c4, *(const float4*)&x[(size_t)(t * 512 + b0 + r) * 32 + c4]);
        }
        __syncthreads();  // xin ready
      } else {
        const int q = (t - 1) & 1;
        if (tid < 128) {
          const int r = tid >> 1, o4 = (tid & 1) * 4;
          const float* yp = &yacc[(size_t)(q * 512 + b0 + r) * 8 + o4];
          float4 v;
          v.x = aldf(yp + 0); v.y = aldf(yp + 1);
          v.z = aldf(yp + 2); v.w = aldf(yp + 3);
          const float4 bb = *(const float4*)&fcb[o4];
          v.x += bb.x; v.y += bb.y; v.z += bb.z; v.w += bb.w;
          if (hc == 0)
            *(float4*)&out[(size_t)((t - kSeq) * 512 + b0 + r) * 8 + o4] = v;
          xin_store(r, o4, v);
        }
        for (int u = tid; u < 384; u += 256) {
          const int r = u / 6, m = u - r * 6;
          xin_store(r, 8 + m * 4,
                    *(const float4*)&ft[(size_t)((t - kSeq) * 512 + b0 + r) * 24 + m * 4]);
        }
        __syncthreads();  // xin ready, yacc reads done
        if (tid == 0) {
          const unsigned old = __hip_atomic_fetch_add(rc + (q * 8 + bc) * 16, 1u,
                                                      __ATOMIC_RELAXED,
                                                      __HIP_MEMORY_SCOPE_AGENT);
          bflag = (old == 31u) ? 1u : 0u;
        }
        __syncthreads();
        if (bflag) {  // last reader zeroes yacc[q] slice for reuse
          for (int u = tid; u < 512; u += 256)
            astf(&yacc[(size_t)q * 512 * 8 + (size_t)b0 * 8 + u], 0.0f);
          relwait();
          __syncthreads();
          if (tid == 0) ast(rc + (q * 8 + bc) * 16, 0u);
        }
      }

      // K-loop: 8 ksteps (jin = kw+4m, m=0..7), PLAIN cacheable A loads
      f32x16 acc00 = zero16(), acc01 = zero16(), acc10 = zero16(), acc11 = zero16();
      const char* hb0 = region((t - 1) & 1, 0, bc);
      unsigned long long abuf[2][16];
#pragma unroll
      for (int i = 0; i < 4; ++i) {  // prefetch group 0
        const size_t off = (size_t)((2 * (kw + 4 * i) + hi5) * 64 + l31) * 16;
        const unsigned long long* p = (const unsigned long long*)(hb0 + off);
        abuf[0][i * 4 + 0] = p[0];
        abuf[0][i * 4 + 1] = p[1];
        const unsigned long long* q2 = (const unsigned long long*)(hb0 + off + 512);
        abuf[0][i * 4 + 2] = q2[0];
        abuf[0][i * 4 + 3] = q2[1];
      }
#pragma unroll
      for (int g = 0; g < 2; ++g) {
        if (g == 0) {
#pragma unroll
          for (int i = 0; i < 4; ++i) {
            const int m = 4 + i;
            const size_t off = (size_t)((2 * (kw + 4 * m) + hi5) * 64 + l31) * 16;
            const unsigned long long* p = (const unsigned long long*)(hb0 + off);
            abuf[1][i * 4 + 0] = p[0];
            abuf[1][i * 4 + 1] = p[1];
            const unsigned long long* q2 = (const unsigned long long*)(hb0 + off + 512);
            abuf[1][i * 4 + 2] = q2[0];
            abuf[1][i * 4 + 3] = q2[1];
          }
        }
#pragma unroll
        for (int i = 0; i < 4; ++i) {
          const int m = g * 4 + i;
          union { unsigned long long u[2]; bf16x8 v; } a0, a1;
          a0.u[0] = abuf[g][i * 4 + 0]; a0.u[1] = abuf[g][i * 4 + 1];
          a1.u[0] = abuf[g][i * 4 + 2]; a1.u[1] = abuf[g][i * 4 + 3];
          acc00 = MFMA32(a0.v, wf[0][m], acc00);
          acc01 = MFMA32(a0.v, wf[1][m], acc01);
          acc10 = MFMA32(a1.v, wf[0][m], acc10);
          acc11 = MFMA32(a1.v, wf[1][m], acc11);
        }
      }
      if (kw < 2) {  // x-part (ksteps 32/33) from LDS xin
#pragma unroll
        for (int ms = 0; ms < 2; ++ms) {
          const int r = ms * 32 + l31;
          const int gx = kw * 2 + hi5;
          const bf16x8 a = *(const bf16x8*)&xin[r * 40 + ((gx ^ (r & 3)) << 3)];
          if (ms == 0) {
            acc00 = MFMA32(a, wf[0][8], acc00);
            acc01 = MFMA32(a, wf[1][8], acc01);
          } else {
            acc10 = MFMA32(a, wf[0][8], acc10);
            acc11 = MFMA32(a, wf[1][8], acc11);
          }
        }
      }
      PARTS_WRITE(acc00, 0, 0); PARTS_WRITE(acc01, 0, 1);
      PARTS_WRITE(acc10, 1, 0); PARTS_WRITE(acc11, 1, 1);
      __syncthreads();
      cell_update();
      __syncthreads();
      h_publish(region(t & 1, 0, bc));
      relwait();
      __syncthreads();
      if (tid == 0) ast(fslot(0, bc, hc), (unsigned)(t + 2));
    }
    // final prediction y(174) -> out[47]
    if (hc == 0) {
      if (kw == 0 && alive)
        alive = pollw(fslot(1, bc, lane & 31), (unsigned)(kT + 1));
      __syncthreads();
      for (int u = tid; u < 512; u += 256) {
        const int r = u >> 3, o = u & 7;
        out[(size_t)(47 * 512 + b0 + r) * 8 + o] =
            aldf(&yacc[(size_t)(b0 + r) * 8 + o]) + fcb[o];
      }
    }
  } else {
    // =========================== LAYER 1 ===========================
    for (int t = 0; t < kT; ++t) {
      if (kw == 0 && alive) {  // h0(t): >=t+2 ; h1(t-1): >=t+1
        const unsigned* slot = (lane < 32)
            ? fslot(0, bc, lane)
            : fslot(1, bc, lane - 32);
        const unsigned thr = (lane < 32) ? (unsigned)(t + 2) : (unsigned)(t + 1);
        alive = pollw(slot, thr);
      }
      __syncthreads();
      acqinv();  // invalidate stale L1/L2 lines; h reads below are cacheable

      f32x16 acc00 = zero16(), acc01 = zero16(), acc10 = zero16(), acc11 = zero16();
      const char* hbA = region(t & 1, 0, bc);   // h0(t), ksteps 0..31
      const char* hbB = region(t & 1, 1, bc);   // h1(t-1), ksteps 32..63
      unsigned long long abuf[2][16];
#pragma unroll
      for (int i = 0; i < 4; ++i) {  // prefetch group 0
        const char* base = hbA;      // m=0..3 -> jin<32
        const size_t off = (size_t)((2 * (kw + 4 * i) + hi5) * 64 + l31) * 16;
        const unsigned long long* p = (const unsigned long long*)(base + off);
        abuf[0][i * 4 + 0] = p[0];
        abuf[0][i * 4 + 1] = p[1];
        const unsigned long long* q2 = (const unsigned long long*)(base + off + 512);
        abuf[0][i * 4 + 2] = q2[0];
        abuf[0][i * 4 + 3] = q2[1];
      }
#pragma unroll
      for (int g = 0; g < 4; ++g) {
        if (g < 3) {
          const int gn = g + 1;
#pragma unroll
          for (int i = 0; i < 4; ++i) {
            const int m = gn * 4 + i;
            const char* base = (m < 8) ? hbA : hbB;
            const int jl = (kw + 4 * m) & 31;
            const size_t off = (size_t)((2 * jl + hi5) * 64 + l31) * 16;
            const unsigned long long* p = (const unsigned long long*)(base + off);
            abuf[gn & 1][i * 4 + 0] = p[0];
            abuf[gn & 1][i * 4 + 1] = p[1];
            const unsigned long long* q2 = (const unsigned long long*)(base + off + 512);
            abuf[gn & 1][i * 4 + 2] = q2[0];
            abuf[gn & 1][i * 4 + 3] = q2[1];
          }
        }
#pragma unroll
        for (int i = 0; i < 4; ++i) {
          const int m = g * 4 + i;
          union { unsigned long long u[2]; bf16x8 v; } a0, a1;
          a0.u[0] = abuf[g & 1][i * 4 + 0]; a0.u[1] = abuf[g & 1][i * 4 + 1];
          a1.u[0] = abuf[g & 1][i * 4 + 2]; a1.u[1] = abuf[g & 1][i * 4 + 3];
          acc00 = MFMA32(a0.v, wf[0][m], acc00);
          acc01 = MFMA32(a0.v, wf[1][m], acc01);
          acc10 = MFMA32(a1.v, wf[0][m], acc10);
          acc11 = MFMA32(a1.v, wf[1][m], acc11);
        }
      }
      PARTS_WRITE(acc00, 0, 0); PARTS_WRITE(acc01, 0, 1);
      PARTS_WRITE(acc10, 1, 0); PARTS_WRITE(acc11, 1, 1);
      __syncthreads();
      // early WAR release: all waves' hbA/hbB loads are consumed (parts
      // written), so L0 may safely overwrite h0 regions.
      if (tid == 0) ast(rdslot(bc, hc), (unsigned)(t + 2));
      cell_update();
      __syncthreads();
      h_publish(region((t & 1) ^ 1, 1, bc));
      if (t >= kSeq - 1) {  // y(t) partials -> yacc[t&1]
        const int q = t & 1;
#pragma unroll
        for (int rep = 0; rep < 2; ++rep) {
          const int i2 = tid + rep * 256;
          const int r = i2 >> 3, o = i2 & 7;
          float s = 0.0f;
#pragma unroll
          for (int h2 = 0; h2 < 16; ++h2)
            s += bf2f(hloc[r * 24 + h2]) * fcwl[o][h2];
          atomicAdd(&yacc[(size_t)(q * 512 + b0 + r) * 8 + o], s);
        }
      }
      relwait();
      __syncthreads();
      if (tid == 0) ast(fslot(1, bc, hc), (unsigned)(t + 2));
    }
  }
}

extern "C" void kernel_launch(void* const* d_in, const int* in_sizes, int n_in,
                              void* d_out, int out_size, void* d_ws, size_t ws_size,
                              hipStream_t stream) {
  (void)in_sizes; (void)n_in; (void)out_size; (void)ws_size;
  hipMemsetAsync((char*)d_ws + kWsZeroBegin, 0, kWsZeroSize, stream);

  const float* x    = (const float*)d_in[0];
  const float* ft   = (const float*)d_in[1];
  const float* h0in = (const float*)d_in[2];
  const float* c0in = (const float*)d_in[3];
  const float* wih0 = (const float*)d_in[4];
  const float* whh0 = (const float*)d_in[5];
  const float* bih0 = (const float*)d_in[6];
  const float* bhh0 = (const float*)d_in[7];
  const float* wih1 = (const float*)d_in[8];
  const float* whh1 = (const float*)d_in[9];
  const float* bih1 = (const float*)d_in[10];
  const float* bhh1 = (const float*)d_in[11];
  const float* fcw  = (const float*)d_in[12];
  const float* fcb  = (const float*)d_in[13];
  float* out = (float*)d_out;
  char* ws = (char*)d_ws;

  void* args[] = {&x, &ft, &h0in, &c0in, &wih0, &whh0, &bih0, &bhh0,
                  &wih1, &whh1, &bih1, &bhh1, &fcw, &fcb, &out, &ws};
  hipError_t err = hipLaunchCooperativeKernel((void*)lstm_persist, dim3(512),
                                              dim3(256), args, 0, stream);
  if (err != hipSuccess) {
    lstm_persist<<<dim3(512), dim3(256), 0, stream>>>(
        x, ft, h0in, c0in, wih0, whh0, bih0, bhh0,
        wih1, whh1, bih1, bhh1, fcw, fcb, out, ws);
  }
}

// Round 7
// 3986.103 us; speedup vs baseline: 10.9894x; 1.4781x over previous
//
#include <hip/hip_runtime.h>

// ---------------------------------------------------------------------------
// Persistent 2-layer LSTM for MI355X (gfx950). Round-11 structure:
//   - Round-4/8 verified skeleton (3390 us): 512 blk x 256 thr, reg weights,
//     fragment-major h regions, agent-scope stores + stamp/poll, yacc decode,
//     rdflag early WAR release.
//   - NEW 1: h regions rotate over 16 step-slots (16 MB ws). An address is
//     rewritten only every 16 steps.
//   - NEW 2: K-loop h reads are PLAIN CACHEABLE uint4 loads (L2-shared across
//     the 32 same-XCD group blocks). Round-4's agent loads bypassed L1/L2 ->
//     48 MB/step from IF at 2.5 TB/s = the measured bound.
//   - NEW 3: agent acquire fence (buffer_inv) only at t%8==0. Any 16-step
//     reuse window contains >=2 fences in every block's program order ->
//     stale lines provably dead before an address is re-read. (Round-10's
//     per-step inv destroyed sharing; this keeps it 7/8 of the time.)
//   - NEW 4: encode skew bound relaxed to 8 (rdflag >= t-6): encode period
//     becomes max(L0,L1) instead of sum; safe now (no address reuse < 16,
//     17 MB live set << IF, WAR gap 16 > skew 8).
// ---------------------------------------------------------------------------

typedef __attribute__((ext_vector_type(8))) short bf16x8;
typedef __attribute__((ext_vector_type(16))) float f32x16;

#define MFMA32(a, b, c) __builtin_amdgcn_mfma_f32_32x32x16_bf16((a), (b), (c), 0, 0, 0)
#define DEV static __device__ __forceinline__

constexpr int kSeq = 128;          // encoder steps
constexpr int kT = 175;            // total lstm steps
constexpr int kRB = 65536;         // bytes per (slot,layer,bc) h region
constexpr int kDepth = 16;         // h slot rotation depth

// workspace layout (bytes)
constexpr size_t kWsHbuf = 0;                                // [16][2][8] = 16 MB
constexpr size_t kWsYacc = (size_t)kDepth * 2 * 8 * kRB;     // [2][512][8] f32
constexpr size_t kWsFlag = kWsYacc + 2ull * 512 * 8 * 4;     // [2][8][32] x 64B
constexpr size_t kWsRc   = kWsFlag + 2ull * 8 * 32 * 64;     // [2][8] x 64B
constexpr size_t kWsRd   = kWsRc + 2ull * 8 * 64;            // [8][32] x 64B
constexpr size_t kWsEnd  = kWsRd + 8ull * 32 * 64;
constexpr size_t kWsZeroBegin = kWsYacc;
constexpr size_t kWsZeroSize  = kWsEnd - kWsYacc;

DEV unsigned short f2bf(float f) {
  unsigned u = __float_as_uint(f);
  u += 0x7fffu + ((u >> 16) & 1u);
  return (unsigned short)(u >> 16);
}
DEV float bf2f(unsigned short s) { return __uint_as_float(((unsigned)s) << 16); }
DEV float sigf(float v) { return 1.0f / (1.0f + __expf(-v)); }
DEV float tanhf_(float v) { float e = __expf(2.0f * v); return 1.0f - 2.0f / (e + 1.0f); }
DEV f32x16 zero16() {
  f32x16 z;
#pragma unroll
  for (int i = 0; i < 16; ++i) z[i] = 0.0f;
  return z;
}
DEV bf16x8 pack8(const float* p) {
  float4 a = *(const float4*)p;
  float4 b = *(const float4*)(p + 4);
  bf16x8 r;
  r[0] = (short)f2bf(a.x); r[1] = (short)f2bf(a.y);
  r[2] = (short)f2bf(a.z); r[3] = (short)f2bf(a.w);
  r[4] = (short)f2bf(b.x); r[5] = (short)f2bf(b.y);
  r[6] = (short)f2bf(b.z); r[7] = (short)f2bf(b.w);
  return r;
}

// device-coherent (agent-scope) primitives ---------------------------------
DEV unsigned ald(const unsigned* p) {
  return __hip_atomic_load(p, __ATOMIC_RELAXED, __HIP_MEMORY_SCOPE_AGENT);
}
DEV void ast(unsigned* p, unsigned v) {
  __hip_atomic_store(p, v, __ATOMIC_RELAXED, __HIP_MEMORY_SCOPE_AGENT);
}
DEV unsigned long long ald64(const unsigned long long* p) {
  return __hip_atomic_load(p, __ATOMIC_RELAXED, __HIP_MEMORY_SCOPE_AGENT);
}
DEV void ast64(unsigned long long* p, unsigned long long v) {
  __hip_atomic_store(p, v, __ATOMIC_RELAXED, __HIP_MEMORY_SCOPE_AGENT);
}
DEV float aldf(const float* p) {
  return __hip_atomic_load(p, __ATOMIC_RELAXED, __HIP_MEMORY_SCOPE_AGENT);
}
DEV void astf(float* p, float v) {
  __hip_atomic_store(p, v, __ATOMIC_RELAXED, __HIP_MEMORY_SCOPE_AGENT);
}
DEV void relwait() {  // drain own coherent stores to the coherence point
  __atomic_signal_fence(__ATOMIC_SEQ_CST);
  __builtin_amdgcn_s_waitcnt(0);
  __atomic_signal_fence(__ATOMIC_SEQ_CST);
}
DEV void acqinv() {  // agent acquire: invalidate stale cached lines
  __builtin_amdgcn_fence(__ATOMIC_ACQUIRE, "agent");
}
// wave-parallel bounded poll: every lane has its own slot/threshold.
DEV bool pollw(const unsigned* slot, unsigned thr) {
  for (int it = 0; it < (1 << 22); ++it) {
    const unsigned v = ald(slot);
    if (__ballot(v < thr) == 0ull) {
      __atomic_signal_fence(__ATOMIC_ACQUIRE);
      return true;
    }
    __builtin_amdgcn_s_sleep(8);
  }
  return false;
}

// parts: [16 (kw,gate)][64 r][17 pad] bf16
#define PARTS_WRITE(accv, ms_, ns_)                                           \
  { const int gate_ = (ns_)*2 + gbit;                                         \
    _Pragma("unroll") for (int rg = 0; rg < 16; ++rg) {                       \
      const int r_ = (ms_)*32 + (rg & 3) + 4 * hi5 + 8 * (rg >> 2);           \
      partsB[((kw * 4 + gate_) * 64 + r_) * 17 + l15] = f2bf((accv)[rg]);     \
    } }

__global__ __launch_bounds__(256, 2) void lstm_persist(
    const float* __restrict__ x, const float* __restrict__ ft,
    const float* __restrict__ h0in, const float* __restrict__ c0in,
    const float* __restrict__ wih0, const float* __restrict__ whh0,
    const float* __restrict__ bih0, const float* __restrict__ bhh0,
    const float* __restrict__ wih1, const float* __restrict__ whh1,
    const float* __restrict__ bih1, const float* __restrict__ bhh1,
    const float* __restrict__ fcw, const float* __restrict__ fcb,
    float* __restrict__ out, char* __restrict__ ws) {
  __shared__ __attribute__((aligned(16))) unsigned short partsB[16 * 64 * 17];
  __shared__ __attribute__((aligned(16))) unsigned short xin[64 * 40];
  __shared__ __attribute__((aligned(16))) unsigned short hloc[64 * 24];
  __shared__ float biasl[4][16];
  __shared__ float fcwl[8][16];
  __shared__ unsigned bflag;

  const int bid = blockIdx.x;
  const int layer = bid >> 8;
  const int idx = bid & 255;
  const int bc = idx & 7;
  const int hc = idx >> 3;
  const int b0 = bc * 64;
  const int u0 = hc * 16;
  const int tid = threadIdx.x;
  const int kw = tid >> 6;
  const int lane = tid & 63;
  const int l31 = lane & 31, l15 = lane & 15, hi5 = lane >> 5, gbit = (lane >> 4) & 1;

  char* hbuf = ws + kWsHbuf;
  float* yacc = (float*)(ws + kWsYacc);
  unsigned* flg = (unsigned*)(ws + kWsFlag);
  unsigned* rc = (unsigned*)(ws + kWsRc);
  unsigned* rdf = (unsigned*)(ws + kWsRd);

  auto fslot = [&](int l, int b, int h) { return flg + (((l * 8) + b) * 32 + h) * 16; };
  auto rdslot = [&](int b, int h) { return rdf + (b * 32 + h) * 16; };
  auto region = [&](int s, int l, int b) -> char* {
    return hbuf + (size_t)(((s * 2) + l) * 8 + b) * kRB;
  };

  bool alive = true;  // wave0 lanes: poll timeout kill-switch

  // ---- one-time: weights -> registers (bf16 B-fragments), index by m ----
  bf16x8 wf[2][16];
#pragma unroll
  for (int ns = 0; ns < 2; ++ns) {
    const int gate = ns * 2 + gbit;
    const int wrow = gate * 512 + u0 + l15;
    if (layer) {
#pragma unroll
      for (int m = 0; m < 16; ++m) {
        const int jg = kw + 4 * m;
        const int k0 = jg * 16 + hi5 * 8;
        const float* p = (k0 < 512) ? (wih1 + wrow * 512 + k0)
                                    : (whh1 + wrow * 512 + (k0 - 512));
        wf[ns][m] = pack8(p);
      }
    } else {
#pragma unroll
      for (int m = 0; m < 8; ++m) {
        const int jg = kw + 4 * m;
        wf[ns][m] = pack8(whh0 + wrow * 512 + jg * 16 + hi5 * 8);
      }
      if (kw < 2) wf[ns][8] = pack8(wih0 + wrow * 32 + kw * 16 + hi5 * 8);
    }
  }

  if (tid < 64) {
    const int g = tid >> 4, h = tid & 15;
    const int row = g * 512 + u0 + h;
    biasl[g][h] = layer ? (bih1[row] + bhh1[row]) : (bih0[row] + bhh0[row]);
  }
  if (layer && tid >= 64 && tid < 192) {
    const int t2 = tid - 64;
    fcwl[t2 >> 4][t2 & 15] = fcw[(t2 >> 4) * 512 + u0 + (t2 & 15)];
  }

  const int own_h = tid & 15;
  const int own_r0 = (tid >> 4) * 4;
  float cst[4];
  {
    const float cv = c0in[layer * 512 + u0 + own_h];
    cst[0] = cst[1] = cst[2] = cst[3] = cv;
  }

  // ---- prologue: write h(-1) into slot 15 (= (-1)&15), stamp 1 ----
  {
    char* dst = region(15, layer, bc);
    if (tid < 128) {
      const int r = tid >> 1, half = tid & 1;
      union { unsigned short s[8]; unsigned long long u[2]; } v;
#pragma unroll
      for (int k2 = 0; k2 < 8; ++k2)
        v.s[k2] = f2bf(h0in[layer * 512 + u0 + half * 8 + k2]);
      unsigned long long* dp =
          (unsigned long long*)(dst + ((u0 >> 3) + half) * 1024 + r * 16);
      ast64(dp, v.u[0]); ast64(dp + 1, v.u[1]);
    }
    relwait();
    __syncthreads();
    if (tid == 0) ast(fslot(layer, bc, hc), 1u);
  }

  auto xin_store = [&](int r, int c4, float4 v) {
    const int gx = c4 >> 3, half = (c4 >> 2) & 1;
    uint2 pv;
    pv.x = (unsigned)f2bf(v.x) | ((unsigned)f2bf(v.y) << 16);
    pv.y = (unsigned)f2bf(v.z) | ((unsigned)f2bf(v.w) << 16);
    *(uint2*)&xin[r * 40 + ((gx ^ (r & 3)) << 3) + half * 4] = pv;
  };

  auto cell_update = [&]() {
#pragma unroll
    for (int i = 0; i < 4; ++i) {
      const int r = own_r0 + i;
      float ig = biasl[0][own_h], fg = biasl[1][own_h];
      float gg = biasl[2][own_h], og = biasl[3][own_h];
#pragma unroll
      for (int w2 = 0; w2 < 4; ++w2) {
        ig += bf2f(partsB[((w2 * 4 + 0) * 64 + r) * 17 + own_h]);
        fg += bf2f(partsB[((w2 * 4 + 1) * 64 + r) * 17 + own_h]);
        gg += bf2f(partsB[((w2 * 4 + 2) * 64 + r) * 17 + own_h]);
        og += bf2f(partsB[((w2 * 4 + 3) * 64 + r) * 17 + own_h]);
      }
      const float cv = sigf(fg) * cst[i] + sigf(ig) * tanhf_(gg);
      cst[i] = cv;
      hloc[r * 24 + own_h] = f2bf(sigf(og) * tanhf_(cv));
    }
  };

  auto h_publish = [&](char* dst) {  // 64 r x 16 units, coherent u64 stores
    if (tid < 128) {
      const int r = tid >> 1, half = tid & 1;
      union { uint4 q; unsigned long long u[2]; } v;
      v.q = *(const uint4*)&hloc[r * 24 + half * 8];
      unsigned long long* dp =
          (unsigned long long*)(dst + ((u0 >> 3) + half) * 1024 + r * 16);
      ast64(dp, v.u[0]); ast64(dp + 1, v.u[1]);
    }
  };

  if (layer == 0) {
    // =========================== LAYER 0 ===========================
    for (int t = 0; t < kT; ++t) {
      // waits: peers' h0(t-1) stamps >= t+1;
      // encode WAR (skew<=8): rdflag >= t-6; decode: flag1 >= t+1 (y ready)
      if (kw == 0 && alive) {
        const unsigned* slot = (lane < 32)
            ? fslot(0, bc, lane)
            : ((t < kSeq) ? rdslot(bc, lane - 32) : fslot(1, bc, lane - 32));
        const unsigned thr = (lane < 32)
            ? (unsigned)(t + 1)
            : ((t < kSeq) ? (unsigned)(t > 6 ? t - 6 : 0) : (unsigned)(t + 1));
        alive = pollw(slot, thr);
      }
      __syncthreads();
      if ((t & 7) == 0) acqinv();  // periodic: kill lines older than reuse gap

      if (t < kSeq) {
#pragma unroll
        for (int it = 0; it < 2; ++it) {
          const int u = tid + it * 256;
          const int r = u >> 3, c4 = (u & 7) * 4;
          xin_store(r, c4, *(const float4*)&x[(size_t)(t * 512 + b0 + r) * 32 + c4]);
        }
        __syncthreads();  // xin ready
      } else {
        const int q = (t - 1) & 1;
        if (tid < 128) {
          const int r = tid >> 1, o4 = (tid & 1) * 4;
          const float* yp = &yacc[(size_t)(q * 512 + b0 + r) * 8 + o4];
          float4 v;
          v.x = aldf(yp + 0); v.y = aldf(yp + 1);
          v.z = aldf(yp + 2); v.w = aldf(yp + 3);
          const float4 bb = *(const float4*)&fcb[o4];
          v.x += bb.x; v.y += bb.y; v.z += bb.z; v.w += bb.w;
          if (hc == 0)
            *(float4*)&out[(size_t)((t - kSeq) * 512 + b0 + r) * 8 + o4] = v;
          xin_store(r, o4, v);
        }
        for (int u = tid; u < 384; u += 256) {
          const int r = u / 6, m = u - r * 6;
          xin_store(r, 8 + m * 4,
                    *(const float4*)&ft[(size_t)((t - kSeq) * 512 + b0 + r) * 24 + m * 4]);
        }
        __syncthreads();  // xin ready, yacc reads done
        if (tid == 0) {
          const unsigned old = __hip_atomic_fetch_add(rc + (q * 8 + bc) * 16, 1u,
                                                      __ATOMIC_RELAXED,
                                                      __HIP_MEMORY_SCOPE_AGENT);
          bflag = (old == 31u) ? 1u : 0u;
        }
        __syncthreads();
        if (bflag) {  // last reader zeroes yacc[q] slice for reuse
          for (int u = tid; u < 512; u += 256)
            astf(&yacc[(size_t)q * 512 * 8 + (size_t)b0 * 8 + u], 0.0f);
          relwait();
          __syncthreads();
          if (tid == 0) ast(rc + (q * 8 + bc) * 16, 0u);
        }
      }

      // K-loop: 8 ksteps (jin = kw+4m, m=0..7), PLAIN CACHED uint4 loads
      f32x16 acc00 = zero16(), acc01 = zero16(), acc10 = zero16(), acc11 = zero16();
      const char* hb0 = region((t + 15) & 15, 0, bc);   // h0(t-1)
      uint4 abuf[2][8];
#pragma unroll
      for (int i = 0; i < 4; ++i) {  // prefetch group 0
        const size_t off = (size_t)((2 * (kw + 4 * i) + hi5) * 64 + l31) * 16;
        abuf[0][i * 2 + 0] = *(const uint4*)(hb0 + off);
        abuf[0][i * 2 + 1] = *(const uint4*)(hb0 + off + 512);
      }
#pragma unroll
      for (int g = 0; g < 2; ++g) {
        if (g == 0) {
#pragma unroll
          for (int i = 0; i < 4; ++i) {
            const int m = 4 + i;
            const size_t off = (size_t)((2 * (kw + 4 * m) + hi5) * 64 + l31) * 16;
            abuf[1][i * 2 + 0] = *(const uint4*)(hb0 + off);
            abuf[1][i * 2 + 1] = *(const uint4*)(hb0 + off + 512);
          }
        }
#pragma unroll
        for (int i = 0; i < 4; ++i) {
          const int m = g * 4 + i;
          union { uint4 q; bf16x8 v; } a0, a1;
          a0.q = abuf[g][i * 2 + 0];
          a1.q = abuf[g][i * 2 + 1];
          acc00 = MFMA32(a0.v, wf[0][m], acc00);
          acc01 = MFMA32(a0.v, wf[1][m], acc01);
          acc10 = MFMA32(a1.v, wf[0][m], acc10);
          acc11 = MFMA32(a1.v, wf[1][m], acc11);
        }
      }
      if (kw < 2) {  // x-part (ksteps 32/33) from LDS xin
#pragma unroll
        for (int ms = 0; ms < 2; ++ms) {
          const int r = ms * 32 + l31;
          const int gx = kw * 2 + hi5;
          const bf16x8 a = *(const bf16x8*)&xin[r * 40 + ((gx ^ (r & 3)) << 3)];
          if (ms == 0) {
            acc00 = MFMA32(a, wf[0][8], acc00);
            acc01 = MFMA32(a, wf[1][8], acc01);
          } else {
            acc10 = MFMA32(a, wf[0][8], acc10);
            acc11 = MFMA32(a, wf[1][8], acc11);
          }
        }
      }
      PARTS_WRITE(acc00, 0, 0); PARTS_WRITE(acc01, 0, 1);
      PARTS_WRITE(acc10, 1, 0); PARTS_WRITE(acc11, 1, 1);
      __syncthreads();
      cell_update();
      __syncthreads();
      h_publish(region(t & 15, 0, bc));
      relwait();
      __syncthreads();
      if (tid == 0) ast(fslot(0, bc, hc), (unsigned)(t + 2));
    }
    // final prediction y(174) -> out[47]
    if (hc == 0) {
      if (kw == 0 && alive)
        alive = pollw(fslot(1, bc, lane & 31), (unsigned)(kT + 1));
      __syncthreads();
      for (int u = tid; u < 512; u += 256) {
        const int r = u >> 3, o = u & 7;
        out[(size_t)(47 * 512 + b0 + r) * 8 + o] =
            aldf(&yacc[(size_t)(b0 + r) * 8 + o]) + fcb[o];
      }
    }
  } else {
    // =========================== LAYER 1 ===========================
    for (int t = 0; t < kT; ++t) {
      if (kw == 0 && alive) {  // h0(t): >=t+2 ; h1(t-1) peers: >=t+1
        const unsigned* slot = (lane < 32)
            ? fslot(0, bc, lane)
            : fslot(1, bc, lane - 32);
        const unsigned thr = (lane < 32) ? (unsigned)(t + 2) : (unsigned)(t + 1);
        alive = pollw(slot, thr);
      }
      __syncthreads();
      if ((t & 7) == 0) acqinv();  // periodic stale-line kill

      f32x16 acc00 = zero16(), acc01 = zero16(), acc10 = zero16(), acc11 = zero16();
      const char* hbA = region(t & 15, 0, bc);          // h0(t), ksteps 0..31
      const char* hbB = region((t + 15) & 15, 1, bc);   // h1(t-1), ksteps 32..63
      uint4 abuf[2][8];
#pragma unroll
      for (int i = 0; i < 4; ++i) {  // prefetch group 0 (m=0..3 -> hbA)
        const size_t off = (size_t)((2 * (kw + 4 * i) + hi5) * 64 + l31) * 16;
        abuf[0][i * 2 + 0] = *(const uint4*)(hbA + off);
        abuf[0][i * 2 + 1] = *(const uint4*)(hbA + off + 512);
      }
#pragma unroll
      for (int g = 0; g < 4; ++g) {
        if (g < 3) {
          const int gn = g + 1;
#pragma unroll
          for (int i = 0; i < 4; ++i) {
            const int m = gn * 4 + i;
            const char* base = (m < 8) ? hbA : hbB;
            const int jl = (kw + 4 * m) & 31;
            const size_t off = (size_t)((2 * jl + hi5) * 64 + l31) * 16;
            abuf[gn & 1][i * 2 + 0] = *(const uint4*)(base + off);
            abuf[gn & 1][i * 2 + 1] = *(const uint4*)(base + off + 512);
          }
        }
#pragma unroll
        for (int i = 0; i < 4; ++i) {
          const int m = g * 4 + i;
          union { uint4 q; bf16x8 v; } a0, a1;
          a0.q = abuf[g & 1][i * 2 + 0];
          a1.q = abuf[g & 1][i * 2 + 1];
          acc00 = MFMA32(a0.v, wf[0][m], acc00);
          acc01 = MFMA32(a0.v, wf[1][m], acc01);
          acc10 = MFMA32(a1.v, wf[0][m], acc10);
          acc11 = MFMA32(a1.v, wf[1][m], acc11);
        }
      }
      PARTS_WRITE(acc00, 0, 0); PARTS_WRITE(acc01, 0, 1);
      PARTS_WRITE(acc10, 1, 0); PARTS_WRITE(acc11, 1, 1);
      __syncthreads();
      // early WAR release: all waves' hbA/hbB loads consumed (parts written)
      if (tid == 0) ast(rdslot(bc, hc), (unsigned)(t + 2));
      cell_update();
      __syncthreads();
      h_publish(region(t & 15, 1, bc));
      if (t >= kSeq - 1) {  // y(t) partials -> yacc[t&1]
        const int q = t & 1;
#pragma unroll
        for (int rep = 0; rep < 2; ++rep) {
          const int i2 = tid + rep * 256;
          const int r = i2 >> 3, o = i2 & 7;
          float s = 0.0f;
#pragma unroll
          for (int h2 = 0; h2 < 16; ++h2)
            s += bf2f(hloc[r * 24 + h2]) * fcwl[o][h2];
          atomicAdd(&yacc[(size_t)(q * 512 + b0 + r) * 8 + o], s);
        }
      }
      relwait();
      __syncthreads();
      if (tid == 0) ast(fslot(1, bc, hc), (unsigned)(t + 2));
    }
  }
}

extern "C" void kernel_launch(void* const* d_in, const int* in_sizes, int n_in,
                              void* d_out, int out_size, void* d_ws, size_t ws_size,
                              hipStream_t stream) {
  (void)in_sizes; (void)n_in; (void)out_size; (void)ws_size;
  hipMemsetAsync((char*)d_ws + kWsZeroBegin, 0, kWsZeroSize, stream);

  const float* x    = (const float*)d_in[0];
  const float* ft   = (const float*)d_in[1];
  const float* h0in = (const float*)d_in[2];
  const float* c0in = (const float*)d_in[3];
  const float* wih0 = (const float*)d_in[4];
  const float* whh0 = (const float*)d_in[5];
  const float* bih0 = (const float*)d_in[6];
  const float* bhh0 = (const float*)d_in[7];
  const float* wih1 = (const float*)d_in[8];
  const float* whh1 = (const float*)d_in[9];
  const float* bih1 = (const float*)d_in[10];
  const float* bhh1 = (const float*)d_in[11];
  const float* fcw  = (const float*)d_in[12];
  const float* fcb  = (const float*)d_in[13];
  float* out = (float*)d_out;
  char* ws = (char*)d_ws;

  void* args[] = {&x, &ft, &h0in, &c0in, &wih0, &whh0, &bih0, &bhh0,
                  &wih1, &whh1, &bih1, &bhh1, &fcw, &fcb, &out, &ws};
  hipError_t err = hipLaunchCooperativeKernel((void*)lstm_persist, dim3(512),
                                              dim3(256), args, 0, stream);
  if (err != hipSuccess) {
    lstm_persist<<<dim3(512), dim3(256), 0, stream>>>(
        x, ft, h0in, c0in, wih0, whh0, bih0, bhh0,
        wih1, whh1, bih1, bhh1, fcw, fcb, out, ws);
  }
}